// Round 1
// baseline (396.774 us; speedup 1.0000x reference)
//
#include <hip/hip_runtime.h>
#include <hip/hip_bf16.h>

// KVEmbedding: out[b,l,:] = table[indices[b,l], :]
// indices: (4096, 200) int   -> 819,200 elements
// table:   (1,000,000, 64) f32
// out:     (4096, 200, 64) f32 = 52,428,800 elements (~210 MB)
//
// Memory-bound gather. Each output row is 64 f32 = 256 B = 16 float4.
// Thread t handles float4 #(t&15) of row (t>>4): coalesced 256B table
// reads and fully coalesced output stores.

__global__ __launch_bounds__(256) void KVEmbedding_56822417326208_kernel(
    const int* __restrict__ idx,
    const float* __restrict__ table,
    float* __restrict__ out,
    int n_rows) {
    long tid = (long)blockIdx.x * blockDim.x + threadIdx.x;
    long total = (long)n_rows * 16;  // 16 float4 per row
    if (tid >= total) return;

    long row = tid >> 4;          // which (b,l) pair
    int  c   = (int)(tid & 15);   // which float4 within the 64-float row

    long t = (long)idx[row];      // table row index
    const float4* __restrict__ src = (const float4*)(table + t * 64);
    float4*       __restrict__ dst = (float4*)(out + row * 64);
    dst[c] = src[c];
}

extern "C" void kernel_launch(void* const* d_in, const int* in_sizes, int n_in,
                              void* d_out, int out_size, void* d_ws, size_t ws_size,
                              hipStream_t stream) {
    const int*   idx   = (const int*)d_in[0];
    const float* table = (const float*)d_in[1];
    // d_in[2] is the dummy scalar; its contribution is exactly 0.
    float* out = (float*)d_out;

    int n_rows = in_sizes[0];             // 4096*200 = 819,200
    long total = (long)n_rows * 16;       // threads (one float4 each)
    int  block = 256;
    long grid  = (total + block - 1) / block;

    KVEmbedding_56822417326208_kernel<<<dim3((unsigned)grid), dim3(block), 0, stream>>>(
        idx, table, out, n_rows);
}